// Round 5
// baseline (395.798 us; speedup 1.0000x reference)
//
#include <hip/hip_runtime.h>
#include <hip/hip_bf16.h>
#include <cstdint>

// ---------------------------------------------------------------------------
// RoPE Multi-Head Self-Attention, MI355X (gfx950)
// B=32, S=577, E=768, H=12, Dh=64.  Inputs fp32, output fp32 (r6-verified).
// Internally bf16 MFMA / fp32 accumulate; qkv workspace bf16.
// Round 12:
//  [C1,C2] convert x, w_qkv -> bf16 into d_out-as-scratch (dead until K4)
//  [K1] qkv = xb @ wb^T           (bf16 DMA staging, r11 chunk-XOR swizzle)
//       NEW r12: T3 "2-phase" double-buffered K-loop.  Old order issued
//       gload_lds then IMMEDIATELY drained it at the next barrier (full
//       global latency exposed, every K-step).  New order per step: issue
//       t+1's loads into buf^1 -> ds_read+16 MFMA on buf -> ONE barrier.
//       Load latency hides under the MFMA block.  K/32=24 steps, unrolled
//       x2 so buffer indices are compile-time constants.
//  [K2] RoPE in-place on q,k patch rows
//  [K3] flash attention (r10 async K/V prefetch + swapped QK^T softmax)
//  [K4] out = O @ bf16(w_proj)^T  (B fp32: loads pre-MFMA, cvt+ds_write
//       post-MFMA -- latency hidden the same way)
// ---------------------------------------------------------------------------

typedef __attribute__((ext_vector_type(8))) short bf16x8;  // 8 bf16 = 4 VGPRs
typedef __attribute__((ext_vector_type(4))) float f32x4;

#define MFMA16(a, b, c) __builtin_amdgcn_mfma_f32_16x16x32_bf16((a), (b), (c), 0, 0, 0)

#define S_LEN 577
#define NHEAD 12
#define DHEAD 64
#define EMB   768
#define F3    2304   // 3*EMB
#define NT_KV 10     // ceil(577/64)
#define BUFO  (128 * 32)   // gemm LDS buffer stride (elements)

// async global->LDS, 16B/lane; LDS dest must be wave-uniform base + lane*16.
__device__ __forceinline__ void gload_lds16(const __hip_bfloat16* g, __hip_bfloat16* l) {
    __builtin_amdgcn_global_load_lds(
        (const __attribute__((address_space(1))) unsigned int*)g,
        (__attribute__((address_space(3))) unsigned int*)l, 16, 0, 0);
}

// pack 2 float4 -> 8 bf16 in a uint4 (16B)
__device__ __forceinline__ uint4 cvt8_f32(float4 a, float4 b) {
    union { uint4 u; __hip_bfloat16 h[8]; } r;
    r.h[0] = __float2bfloat16(a.x); r.h[1] = __float2bfloat16(a.y);
    r.h[2] = __float2bfloat16(a.z); r.h[3] = __float2bfloat16(a.w);
    r.h[4] = __float2bfloat16(b.x); r.h[5] = __float2bfloat16(b.y);
    r.h[6] = __float2bfloat16(b.z); r.h[7] = __float2bfloat16(b.w);
    return r.u;
}

// load 8 consecutive fp32, convert to bf16 packed in a uint4 (16B)
__device__ __forceinline__ uint4 load8_f32(const float* p) {
    return cvt8_f32(*(const float4*)p, *(const float4*)(p + 4));
}

// ---------------------------------------------------------------------------
// C1/C2: fp32 -> bf16 bulk convert (n must be a multiple of 8; ours are)
// ---------------------------------------------------------------------------
__global__ __launch_bounds__(256) void cvt_f32_bf16(
    const float* __restrict__ src, __hip_bfloat16* __restrict__ dst, int n8)
{
    const int i = blockIdx.x * 256 + threadIdx.x;
    if (i < n8)
        *(uint4*)(dst + (size_t)i * 8) = load8_f32(src + (size_t)i * 8);
}

// ---------------------------------------------------------------------------
// K1/K4: C[m][n] = sum_k A[m][k] * B[n][k]
// A: bf16, row stride lda, staged via global_load_lds DMA.
// B: BF32 ? fp32 register staging (load pre-MFMA, cvt+ds_write post-MFMA)
//         : bf16 DMA staging.  Row stride ldb.
// C: CF32 ? fp32 : bf16.  N%128==0, K%64==0; M guarded.
// 128x128 tile, BK=32, 16x16x32 MFMA, 4 waves x 4x4 acc frags.
// r11 chunk-XOR swizzle: LDS slot s of row r holds global chunk s^((r>>1)&3)
// (staging pre-swizzles the GLOBAL source; reads use quad^((lane15>>1)&3)).
// r12 2-phase double buffer: one barrier per K-step; next tile's loads are
// in flight across the ds_read+MFMA block (T3 minimum recipe).
// ---------------------------------------------------------------------------
template<bool BF32, bool CF32>
__global__ __launch_bounds__(256) void gemm_a_dma(
    const __hip_bfloat16* __restrict__ A, int lda,
    const void* __restrict__ Bv, int ldb,
    void* __restrict__ Cv, int M, int N, int K)
{
    __shared__ __hip_bfloat16 As[2 * BUFO];   // [buf][row][k-swz], 64B rows
    __shared__ __hip_bfloat16 Bs[2 * BUFO];

    const int t      = threadIdx.x;
    const int l      = t & 63;
    const int w      = t >> 6;
    const int lane15 = l & 15;
    const int quad   = l >> 4;

    const int n0 = blockIdx.x * 128;
    const int m0 = blockIdx.y * 128;
    const int wm = (w >> 1) * 64;
    const int wn = (w & 1) * 64;

    const int srow   = t >> 2;   // 0..63
    const int schunk = t & 3;    // 0..3 (16B chunks)
    const int fsw    = (t >> 3) & 3;
    const int gchunk = schunk ^ fsw;          // swizzled global chunk

    int ar0 = m0 + srow;       if (ar0 > M - 1) ar0 = M - 1;
    int ar1 = m0 + 64 + srow;  if (ar1 > M - 1) ar1 = M - 1;
    const int br0 = n0 + srow;
    const int br1 = n0 + 64 + srow;

    const __hip_bfloat16* pa0 = A + (size_t)ar0 * lda + gchunk * 8;
    const __hip_bfloat16* pa1 = A + (size_t)ar1 * lda + gchunk * 8;
    const size_t b0off = (size_t)br0 * ldb + gchunk * 8;
    const size_t b1off = (size_t)br1 * ldb + gchunk * 8;

    __hip_bfloat16* lAs0 = As + srow * 32 + schunk * 8;          // buf0 slots
    __hip_bfloat16* lAs1 = As + (64 + srow) * 32 + schunk * 8;
    __hip_bfloat16* lBs0 = Bs + srow * 32 + schunk * 8;
    __hip_bfloat16* lBs1 = Bs + (64 + srow) * 32 + schunk * 8;

    // read-side swizzle: ((row>>1)&3) == ((lane15>>1)&3) for all frag rows
    const int rsw = (quad ^ ((lane15 >> 1) & 3)) * 8;

    f32x4 acc[4][4] = {};

    // ---- prologue: stage K-step 0 into buffer 0 ----
    gload_lds16(pa0, lAs0);
    gload_lds16(pa1, lAs1);
    if constexpr (BF32) {
        *(uint4*)lBs0 = load8_f32((const float*)Bv + b0off);
        *(uint4*)lBs1 = load8_f32((const float*)Bv + b1off);
    } else {
        gload_lds16((const __hip_bfloat16*)Bv + b0off, lBs0);
        gload_lds16((const __hip_bfloat16*)Bv + b1off, lBs1);
    }
    __syncthreads();

    // One 2-phase step: compute on buffer CO while staging kn into buffer NO.
#define GEMM_STEP(kn, CO, NO)                                                 \
    {                                                                         \
        float4 g0 = {}, g1 = {}, g2 = {}, g3 = {};                            \
        const bool has_next = (kn) < K;                                       \
        if (has_next) {                                                       \
            gload_lds16(pa0 + (kn), lAs0 + (NO));                             \
            gload_lds16(pa1 + (kn), lAs1 + (NO));                             \
            if constexpr (BF32) {                                             \
                const float* pb0 = (const float*)Bv + b0off + (kn);           \
                const float* pb1 = (const float*)Bv + b1off + (kn);           \
                g0 = *(const float4*)pb0; g1 = *(const float4*)(pb0 + 4);     \
                g2 = *(const float4*)pb1; g3 = *(const float4*)(pb1 + 4);     \
            } else {                                                          \
                gload_lds16((const __hip_bfloat16*)Bv + b0off + (kn), lBs0 + (NO)); \
                gload_lds16((const __hip_bfloat16*)Bv + b1off + (kn), lBs1 + (NO)); \
            }                                                                 \
        }                                                                     \
        bf16x8 a[4], b[4];                                                    \
        _Pragma("unroll")                                                     \
        for (int i = 0; i < 4; ++i)                                           \
            a[i] = *(const bf16x8*)(As + (CO) + (wm + i * 16 + lane15) * 32 + rsw); \
        _Pragma("unroll")                                                     \
        for (int j = 0; j < 4; ++j)                                           \
            b[j] = *(const bf16x8*)(Bs + (CO) + (wn + j * 16 + lane15) * 32 + rsw); \
        _Pragma("unroll")                                                     \
        for (int i = 0; i < 4; ++i)                                           \
            _Pragma("unroll")                                                 \
            for (int j = 0; j < 4; ++j)                                       \
                acc[i][j] = MFMA16(a[i], b[j], acc[i][j]);                    \
        if constexpr (BF32) {                                                 \
            if (has_next) {                                                   \
                *(uint4*)(lBs0 + (NO)) = cvt8_f32(g0, g1);                    \
                *(uint4*)(lBs1 + (NO)) = cvt8_f32(g2, g3);                    \
            }                                                                 \
        }                                                                     \
        __syncthreads();                                                      \
    }

    for (int k0 = 0; k0 < K; k0 += 64) {
        GEMM_STEP(k0 + 32, 0,    BUFO)     // compute buf0, stage buf1
        GEMM_STEP(k0 + 64, BUFO, 0)        // compute buf1, stage buf0
    }
#undef GEMM_STEP

    // epilogue: C/D layout col=lane&15, row=quad*4+reg
    #pragma unroll
    for (int i = 0; i < 4; ++i) {
        #pragma unroll
        for (int r = 0; r < 4; ++r) {
            const int m = m0 + wm + i * 16 + quad * 4 + r;
            if (m < M) {
                #pragma unroll
                for (int j = 0; j < 4; ++j) {
                    const int n = n0 + wn + j * 16 + lane15;
                    if constexpr (CF32)
                        ((float*)Cv)[(size_t)m * N + n] = acc[i][j][r];
                    else
                        ((__hip_bfloat16*)Cv)[(size_t)m * N + n] = __float2bfloat16(acc[i][j][r]);
                }
            }
        }
    }
}

// ---------------------------------------------------------------------------
// K2: RoPE in-place on q and k for patch tokens (s >= 1) — r6-verified.
// ---------------------------------------------------------------------------
__global__ __launch_bounds__(256) void rope_kernel(__hip_bfloat16* __restrict__ qkv)
{
    const int p = blockIdx.x;    // 0..575 patch index
    const int b = blockIdx.y;
    const int l = threadIdx.x & 63;
    const int w = threadIdx.x >> 6;

    const int jj   = l & 31;
    const float i2 = (float)((jj >> 1) * 2);
    const float dv = __expf(-i2 * 0.28782313662425576f);   // ln(10000)/32
    const float inv = 1.0f / (23.0f + 1e-8f);
    const float cx = (float)(p % 24) * inv;
    const float cy = (float)(p / 24) * inv;
    const float ang = ((l < 32) ? cx : cy) * dv;
    const float c = __cosf(ang);
    const float s = __sinf(ang);
    const int nb = (l & 32) | ((jj + 31) & 31);   // lane of (j-1)%32, same half

    const size_t rowbase = ((size_t)(b * S_LEN + 1 + p)) * F3;

    for (int pr = w; pr < 24; pr += 4) {
        const int part = pr / 12;    // 0=q, 1=k
        const int h    = pr % 12;
        const size_t off = rowbase + (size_t)part * EMB + h * DHEAD + l;
        float v  = __bfloat162float(qkv[off]);
        float vp = __shfl(v, nb, 64);
        qkv[off] = __float2bfloat16(v * c + vp * s);
    }
}

// ---------------------------------------------------------------------------
// K3: MFMA flash attention, 512 threads (8 waves), Q tile = 128 rows.
// grid (qt=5, h=12, b=32). Wave w owns q rows w*16..w*16+15 of the tile.
// Q pre-scaled by 0.125. O written with row stride ldo (aliased onto qkv's
// q-region; each block overwrites exactly the q-cells only it reads).
//
// Ps aliased onto the Qs LDS region (Qs dead after frag load): LDS 36864 B
// -> 4 blocks/CU.  P write rows are wave-private (w*16+lane15), so the P
// round-trip needs only a same-wave lgkmcnt drain.
//
// r10a T14 async-STAGE: tile t+1's K/V global loads issue before barrier B;
// barrier B is raw s_barrier + lgkmcnt(0) only (NO vmcnt drain) so the loads
// stay in flight across the compute phase.  Barrier A (__syncthreads) drains
// vmcnt right where the data is consumed (LDS staging writes).
//
// r10b swapped QK^T: sf = mfma(Kfrag, Qfrag) gives S^T[key][q]; lane owns
// q=lane15's 64 keys (16 regs + quad-folds at xor16/xor32).  Scalar m/l.
// alpha/l broadcast to O-layout rows (q=quad*4+r) via 4 lane-reads.
// ---------------------------------------------------------------------------
__global__ __launch_bounds__(512) void attn_kernel(
    const __hip_bfloat16* __restrict__ qkv,
    __hip_bfloat16* __restrict__ attn_out, int ldo)
{
    __shared__ __hip_bfloat16 Qs[128][72];     // Q frags, then aliased as Ps
    __shared__ __hip_bfloat16 Ks[64][72];
    __shared__ __hip_bfloat16 Vt[64][72];      // transposed: Vt[d][s]

    const int t      = threadIdx.x;
    const int l      = t & 63;
    const int w      = t >> 6;     // 0..7
    const int lane15 = l & 15;
    const int quad   = l >> 4;

    const int q0 = blockIdx.x * 128;
    const int h  = blockIdx.y;
    const int b  = blockIdx.z;

    // staging index split (fixed per thread)
    const int krow = t >> 3, kseg = t & 7;   // K: row 0..63, 16B chunk 0..7
    const int vs   = t & 63, vdg = t >> 6;   // V: s 0..63, dim-group 0..7

    // ---- issue tile-0 K/V prefetch ----
    uint4 ku, vu;
    {
        int gk = krow; if (gk > S_LEN - 1) gk = S_LEN - 1;
        ku = ((const uint4*)(qkv + (size_t)(b * S_LEN + gk) * F3 + EMB + h * DHEAD))[kseg];
        int gv = vs;  if (gv > S_LEN - 1) gv = S_LEN - 1;
        vu = ((const uint4*)(qkv + (size_t)(b * S_LEN + gv) * F3 + 2 * EMB + h * DHEAD))[vdg];
    }

    // ---- stage Q (scaled): row = t>>2 (0..127), seg = t&3 (16 elems) ----
    {
        const int row = t >> 2, seg = t & 3;
        int gq = q0 + row; if (gq > S_LEN - 1) gq = S_LEN - 1;
        const uint4* src = (const uint4*)(qkv + (size_t)(b * S_LEN + gq) * F3 + h * DHEAD + seg * 16);
        uint4 u0 = src[0], u1 = src[1];
        const __hip_bfloat16* e0 = (const __hip_bfloat16*)&u0;
        const __hip_bfloat16* e1 = (const __hip_bfloat16*)&u1;
        #pragma unroll
        for (int i = 0; i < 8; ++i) {
            Qs[row][seg * 16 + i]     = __float2bfloat16(__bfloat162float(e0[i]) * 0.125f);
            Qs[row][seg * 16 + 8 + i] = __float2bfloat16(__bfloat162float(e1[i]) * 0.125f);
        }
    }
    __syncthreads();

    // B-operand frags for Q: B[n=lane&15 (q row)][k=quad*8+j]  (held whole loop)
    bf16x8 qf0 = *(const bf16x8*)&Qs[w * 16 + lane15][quad * 8];
    bf16x8 qf1 = *(const bf16x8*)&Qs[w * 16 + lane15][32 + quad * 8];

    f32x4 o[4] = {};                       // O[q=quad*4+r][d=ci*16+lane15]
    float m_i = -3.0e38f;                  // softmax state for q = lane15 (scalar)
    float l_i = 0.f;

    for (int ti = 0; ti < NT_KV; ++ti) {
        __syncthreads();   // A: prior tile's LDS reads done; vmcnt drain = consume prefetch
        // ---- write prefetched K tile: Ks[krow][kseg*8..] ----
        *(uint4*)&Ks[krow][kseg * 8] = ku;
        // ---- write prefetched V tile transposed ----
        {
            const __hip_bfloat16* e0 = (const __hip_bfloat16*)&vu;
            #pragma unroll
            for (int i = 0; i < 8; ++i)
                Vt[vdg * 8 + i][vs] = e0[i];
        }
        // ---- issue NEXT tile's K/V prefetch (stays in flight across B) ----
        if (ti + 1 < NT_KV) {
            int gk = (ti + 1) * 64 + krow; if (gk > S_LEN - 1) gk = S_LEN - 1;
            ku = ((const uint4*)(qkv + (size_t)(b * S_LEN + gk) * F3 + EMB + h * DHEAD))[kseg];
            int gv = (ti + 1) * 64 + vs;  if (gv > S_LEN - 1) gv = S_LEN - 1;
            vu = ((const uint4*)(qkv + (size_t)(b * S_LEN + gv) * F3 + 2 * EMB + h * DHEAD))[vdg];
        }
        // B: LDS writes visible; do NOT drain vmcnt (prefetch in flight)
        asm volatile("s_waitcnt lgkmcnt(0)" ::: "memory");
        __builtin_amdgcn_s_barrier();
        asm volatile("" ::: "memory");

        // ---- S^T = K Q^T: sf[nt][r] = S[key=nt*16+quad*4+r][q=lane15] ----
        f32x4 sf[4];
        #pragma unroll
        for (int nt = 0; nt < 4; ++nt) {
            f32x4 z = {0.f, 0.f, 0.f, 0.f};
            bf16x8 k0f = *(const bf16x8*)&Ks[nt * 16 + lane15][quad * 8];
            bf16x8 k1f = *(const bf16x8*)&Ks[nt * 16 + lane15][32 + quad * 8];
            z = MFMA16(k0f, qf0, z);
            z = MFMA16(k1f, qf1, z);
            sf[nt] = z;
        }
        const int s0 = ti * 64;
        #pragma unroll
        for (int nt = 0; nt < 4; ++nt)
            #pragma unroll
            for (int r = 0; r < 4; ++r)
                if (s0 + nt * 16 + quad * 4 + r >= S_LEN) sf[nt][r] = -1e30f;

        // ---- row max for q=lane15: 16 local + fold across quads ----
        float mx = fmaxf(fmaxf(sf[0][0], sf[0][1]), fmaxf(sf[0][2], sf[0][3]));
        #pragma unroll
        for (int nt = 1; nt < 4; ++nt)
            mx = fmaxf(mx, fmaxf(fmaxf(sf[nt][0], sf[nt][1]), fmaxf(sf[nt][2], sf[nt][3])));
        mx = fmaxf(mx, __shfl_xor(mx, 16, 64));
        mx = fmaxf(mx, __shfl_xor(mx, 32, 64));

        const float mnew  = fmaxf(m_i, mx);
        const float alpha = __expf(m_i - mnew);
        m_i = mnew;

        // ---- P = exp(S - m), row sum ----
        float sum = 0.f;
        #pragma unroll
        for (int nt = 0; nt < 4; ++nt) {
            #pragma unroll
            for (int r = 0; r < 4; ++r) {
                sf[nt][r] = __expf(sf[nt][r] - mnew);
                sum += sf[nt][r];
            }
        }
        sum += __shfl_xor(sum, 16, 64);
        sum += __shfl_xor(sum, 32, 64);
        l_i = l_i * alpha + sum;

        // ---- broadcast alpha to O-layout rows (q = quad*4+r lives in lane quad*4+r) ----
        float af[4];
        #pragma unroll
        for (int r = 0; r < 4; ++r)
            af[r] = __shfl(alpha, quad * 4 + r, 64);
        #pragma unroll
        for (int ci = 0; ci < 4; ++ci)
            #pragma unroll
            for (int r = 0; r < 4; ++r)
                o[ci][r] *= af[r];

        // ---- P: S^T lane layout -> LDS [q][key] (wave-private rows) ----
        #pragma unroll
        for (int nt = 0; nt < 4; ++nt)
            #pragma unroll
            for (int r = 0; r < 4; ++r)
                Qs[w * 16 + lane15][nt * 16 + quad * 4 + r] = __float2bfloat16(sf[nt][r]);
        asm volatile("s_waitcnt lgkmcnt(0)" ::: "memory");

        // ---- O += P V ----
        #pragma unroll
        for (int s32 = 0; s32 < 2; ++s32) {
            bf16x8 pa = *(const bf16x8*)&Qs[w * 16 + lane15][s32 * 32 + quad * 8];
            #pragma unroll
            for (int ci = 0; ci < 4; ++ci) {
                bf16x8 vb = *(const bf16x8*)&Vt[ci * 16 + lane15][s32 * 32 + quad * 8];
                o[ci] = MFMA16(pa, vb, o[ci]);
            }
        }
    }

    // ---- epilogue: O / l -> attn_out; l for row q=quad*4+r from lane quad*4+r ----
    #pragma unroll
    for (int r = 0; r < 4; ++r) {
        const float lr = __shfl(l_i, quad * 4 + r, 64);
        const int q = q0 + w * 16 + quad * 4 + r;
        if (q < S_LEN) {
            const float rl = 1.0f / lr;
            #pragma unroll
            for (int ci = 0; ci < 4; ++ci) {
                attn_out[(size_t)(b * S_LEN + q) * ldo + h * DHEAD + ci * 16 + lane15] =
                    __float2bfloat16(o[ci][r] * rl);
            }
        }
    }
}

// ---------------------------------------------------------------------------
extern "C" void kernel_launch(void* const* d_in, const int* in_sizes, int n_in,
                              void* d_out, int out_size, void* d_ws, size_t ws_size,
                              hipStream_t stream) {
    const float* x      = (const float*)d_in[0];
    const float* w_qkv  = (const float*)d_in[1];
    const float* w_proj = (const float*)d_in[2];
    for (int i = 0; i < n_in; ++i) {
        if      (in_sizes[i] == 32 * S_LEN * EMB) x      = (const float*)d_in[i];
        else if (in_sizes[i] == F3 * EMB)         w_qkv  = (const float*)d_in[i];
        else if (in_sizes[i] == EMB * EMB)        w_proj = (const float*)d_in[i];
    }
    float* out = (float*)d_out;     // fp32 output (r6-verified)

    const int Mrows = 32 * S_LEN;           // 18464
    const int NX    = Mrows * EMB;          // 14,180,352 (mult of 8)
    const int NWQ   = F3 * EMB;             // 1,769,472  (mult of 8)

    __hip_bfloat16* qkv = (__hip_bfloat16*)d_ws;        // [M][2304] bf16, 81.1 MiB
    // d_out as scratch until K4 overwrites it: xb (28.4 MB) + wb (3.4 MB) < 56.7 MB
    __hip_bfloat16* xb  = (__hip_bfloat16*)d_out;
    __hip_bfloat16* wb  = xb + (size_t)NX;

    // C1/C2: fp32 -> bf16 converts into d_out scratch
    cvt_f32_bf16<<<NX / 8 / 256, 256, 0, stream>>>(x, xb, NX / 8);
    cvt_f32_bf16<<<NWQ / 8 / 256, 256, 0, stream>>>(w_qkv, wb, NWQ / 8);
    // K1: qkv = xb @ wb^T  (pure-bf16 DMA staging, bf16 C)
    gemm_a_dma<false, false><<<dim3(F3 / 128, (Mrows + 127) / 128), 256, 0, stream>>>(
        xb, EMB, wb, EMB, qkv, Mrows, F3, EMB);
    // K2: RoPE on q,k patch rows
    rope_kernel<<<dim3(576, 32), 256, 0, stream>>>(qkv);
    // K3: attention (512 thr, 128-row Q tiles); O overwrites q-region of qkv
    attn_kernel<<<dim3((S_LEN + 127) / 128, NHEAD, 32), 512, 0, stream>>>(qkv, qkv, F3);
    // K4: out = O @ bf16(w_proj)^T  (A DMA bf16 stride F3; B fp32 convert; C fp32)
    gemm_a_dma<true, true><<<dim3(EMB / 128, (Mrows + 127) / 128), 256, 0, stream>>>(
        qkv, F3, w_proj, EMB, out, Mrows, EMB, EMB);
}

// Round 6
// 388.970 us; speedup vs baseline: 1.0176x; 1.0176x over previous
//
#include <hip/hip_runtime.h>
#include <hip/hip_bf16.h>
#include <cstdint>

// ---------------------------------------------------------------------------
// RoPE Multi-Head Self-Attention, MI355X (gfx950)
// B=32, S=577, E=768, H=12, Dh=64.  Inputs fp32, output fp32 (r6-verified).
// Internally bf16 MFMA / fp32 accumulate; qkv workspace bf16.
// Round 13:
//  [C1,C2] convert x, w_qkv -> bf16 into d_out-as-scratch (dead until K4)
//  [K1] qkv = xb @ wb^T           (bf16 DMA staging, r11 chunk-XOR swizzle)
//       NEW r13: T4 counted-vmcnt depth-2 pipeline, TRIPLE buffer.
//       r12's 2-phase still ended each step with __syncthreads (vmcnt(0)
//       drain -> this step's loads must land before the barrier; MfmaUtil
//       stuck at 26%).  Now: issue stage(s+2) -> compute buf(s%3) ->
//       s_waitcnt vmcnt(4) lgkmcnt(0) -> s_barrier.  vmcnt(4) leaves the
//       just-issued loads IN FLIGHT across the barrier; only stage(s+1)
//       (issued a full step ago) must have retired.  24 steps, 3-unrolled
//       so buffer offsets are compile-time.  K must be mult of 96 (768 ok).
//  [K2] RoPE in-place on q,k patch rows
//  [K3] flash attention (r10 async K/V prefetch + swapped QK^T softmax)
//  [K4] out = O @ bf16(w_proj)^T  (B f32 loads issued FIRST each step so
//       the post-MFMA ds_write's implicit wait retires only them, leaving
//       the A gloads flying; explicit wait = vmcnt(2))
// ---------------------------------------------------------------------------

typedef __attribute__((ext_vector_type(8))) short bf16x8;  // 8 bf16 = 4 VGPRs
typedef __attribute__((ext_vector_type(4))) float f32x4;

#define MFMA16(a, b, c) __builtin_amdgcn_mfma_f32_16x16x32_bf16((a), (b), (c), 0, 0, 0)

#define S_LEN 577
#define NHEAD 12
#define DHEAD 64
#define EMB   768
#define F3    2304   // 3*EMB
#define NT_KV 10     // ceil(577/64)
#define BUFO  (128 * 32)   // gemm LDS buffer stride (elements, 8 KiB)

// async global->LDS, 16B/lane; LDS dest must be wave-uniform base + lane*16.
__device__ __forceinline__ void gload_lds16(const __hip_bfloat16* g, __hip_bfloat16* l) {
    __builtin_amdgcn_global_load_lds(
        (const __attribute__((address_space(1))) unsigned int*)g,
        (__attribute__((address_space(3))) unsigned int*)l, 16, 0, 0);
}

// pack 2 float4 -> 8 bf16 in a uint4 (16B)
__device__ __forceinline__ uint4 cvt8_f32(float4 a, float4 b) {
    union { uint4 u; __hip_bfloat16 h[8]; } r;
    r.h[0] = __float2bfloat16(a.x); r.h[1] = __float2bfloat16(a.y);
    r.h[2] = __float2bfloat16(a.z); r.h[3] = __float2bfloat16(a.w);
    r.h[4] = __float2bfloat16(b.x); r.h[5] = __float2bfloat16(b.y);
    r.h[6] = __float2bfloat16(b.z); r.h[7] = __float2bfloat16(b.w);
    return r.u;
}

// load 8 consecutive fp32, convert to bf16 packed in a uint4 (16B)
__device__ __forceinline__ uint4 load8_f32(const float* p) {
    return cvt8_f32(*(const float4*)p, *(const float4*)(p + 4));
}

// ---------------------------------------------------------------------------
// C1/C2: fp32 -> bf16 bulk convert (n must be a multiple of 8; ours are)
// ---------------------------------------------------------------------------
__global__ __launch_bounds__(256) void cvt_f32_bf16(
    const float* __restrict__ src, __hip_bfloat16* __restrict__ dst, int n8)
{
    const int i = blockIdx.x * 256 + threadIdx.x;
    if (i < n8)
        *(uint4*)(dst + (size_t)i * 8) = load8_f32(src + (size_t)i * 8);
}

// ---------------------------------------------------------------------------
// K1/K4: C[m][n] = sum_k A[m][k] * B[n][k]
// A: bf16, row stride lda, staged via global_load_lds DMA (depth 2).
// B: BF32 ? fp32 register staging depth 1 (issue pre-MFMA, cvt+ds_write post)
//         : bf16 DMA staging depth 2.  Row stride ldb.
// C: CF32 ? fp32 : bf16.  N%128==0, K%96==0; M guarded.
// 128x128 tile, BK=32, 16x16x32 MFMA, 4 waves x 4x4 acc frags.
// r11 chunk-XOR swizzle: LDS slot s of row r holds global chunk s^((r>>1)&3)
// (staging pre-swizzles the GLOBAL source; reads use quad^((lane15>>1)&3)).
// r13 counted-vmcnt triple buffer: loads stay in flight across barriers.
// ---------------------------------------------------------------------------
template<bool BF32, bool CF32>
__global__ __launch_bounds__(256) void gemm_a_dma(
    const __hip_bfloat16* __restrict__ A, int lda,
    const void* __restrict__ Bv, int ldb,
    void* __restrict__ Cv, int M, int N, int K)
{
    __shared__ __hip_bfloat16 As[3 * BUFO];   // [buf][row][k-swz], 64B rows
    __shared__ __hip_bfloat16 Bs[3 * BUFO];

    const int t      = threadIdx.x;
    const int l      = t & 63;
    const int w      = t >> 6;
    const int lane15 = l & 15;
    const int quad   = l >> 4;

    const int n0 = blockIdx.x * 128;
    const int m0 = blockIdx.y * 128;
    const int wm = (w >> 1) * 64;
    const int wn = (w & 1) * 64;

    const int srow   = t >> 2;   // 0..63
    const int schunk = t & 3;    // 0..3 (16B chunks)
    const int fsw    = (t >> 3) & 3;
    const int gchunk = schunk ^ fsw;          // swizzled global chunk

    int ar0 = m0 + srow;       if (ar0 > M - 1) ar0 = M - 1;
    int ar1 = m0 + 64 + srow;  if (ar1 > M - 1) ar1 = M - 1;
    const int br0 = n0 + srow;
    const int br1 = n0 + 64 + srow;

    const __hip_bfloat16* pa0 = A + (size_t)ar0 * lda + gchunk * 8;
    const __hip_bfloat16* pa1 = A + (size_t)ar1 * lda + gchunk * 8;
    const size_t b0off = (size_t)br0 * ldb + gchunk * 8;
    const size_t b1off = (size_t)br1 * ldb + gchunk * 8;

    __hip_bfloat16* lAs0 = As + srow * 32 + schunk * 8;          // buf0 slots
    __hip_bfloat16* lAs1 = As + (64 + srow) * 32 + schunk * 8;
    __hip_bfloat16* lBs0 = Bs + srow * 32 + schunk * 8;
    __hip_bfloat16* lBs1 = Bs + (64 + srow) * 32 + schunk * 8;

    // read-side swizzle: ((row>>1)&3) == ((lane15>>1)&3) for all frag rows
    const int rsw = (quad ^ ((lane15 >> 1) & 3)) * 8;

    f32x4 acc[4][4] = {};

    // ---- prologue: stage step0 -> buf0, step1 -> buf1 ----
    if constexpr (BF32) {
        // B(0) f32 loads FIRST (their retire must not wait on A gloads)
        float4 h0, h1, h2, h3;
        {
            const float* pb0 = (const float*)Bv + b0off;
            const float* pb1 = (const float*)Bv + b1off;
            h0 = *(const float4*)pb0; h1 = *(const float4*)(pb0 + 4);
            h2 = *(const float4*)pb1; h3 = *(const float4*)(pb1 + 4);
        }
        gload_lds16(pa0, lAs0);                 // A(0) -> buf0
        gload_lds16(pa1, lAs1);
        gload_lds16(pa0 + 32, lAs0 + BUFO);     // A(32) -> buf1
        gload_lds16(pa1 + 32, lAs1 + BUFO);
        *(uint4*)lBs0 = cvt8_f32(h0, h1);       // implicit wait retires B only
        *(uint4*)lBs1 = cvt8_f32(h2, h3);
        asm volatile("s_waitcnt vmcnt(2) lgkmcnt(0)" ::: "memory");  // A(0) done
    } else {
        gload_lds16(pa0, lAs0);                 // step0 -> buf0
        gload_lds16(pa1, lAs1);
        gload_lds16((const __hip_bfloat16*)Bv + b0off, lBs0);
        gload_lds16((const __hip_bfloat16*)Bv + b1off, lBs1);
        gload_lds16(pa0 + 32, lAs0 + BUFO);     // step1 -> buf1
        gload_lds16(pa1 + 32, lAs1 + BUFO);
        gload_lds16((const __hip_bfloat16*)Bv + b0off + 32, lBs0 + BUFO);
        gload_lds16((const __hip_bfloat16*)Bv + b1off + 32, lBs1 + BUFO);
        asm volatile("s_waitcnt vmcnt(4) lgkmcnt(0)" ::: "memory");  // step0 done
    }
    __builtin_amdgcn_s_barrier();

    // One step: compute buf CO (k=KC); stage B(k=KC+32)->buf NB (BF32 path),
    // A/B(k=KC+64)->buf NA; counted-vmcnt wait; barrier.
#define GEMM_STEP(KC, CO, NB, NA)                                             \
    {                                                                         \
        const int ka = (KC) + 64;                                             \
        const int kb = (KC) + 32;                                             \
        const bool hasA = ka < K;                                             \
        const bool hasB = kb < K;                                             \
        float4 g0 = {}, g1 = {}, g2 = {}, g3 = {};                            \
        if constexpr (BF32) {                                                 \
            if (hasB) {   /* issue B f32 FIRST (in-order vmcnt retire) */     \
                const float* pb0 = (const float*)Bv + b0off + kb;             \
                const float* pb1 = (const float*)Bv + b1off + kb;             \
                g0 = *(const float4*)pb0; g1 = *(const float4*)(pb0 + 4);     \
                g2 = *(const float4*)pb1; g3 = *(const float4*)(pb1 + 4);     \
            }                                                                 \
            if (hasA) {                                                       \
                gload_lds16(pa0 + ka, lAs0 + (NA) * BUFO);                    \
                gload_lds16(pa1 + ka, lAs1 + (NA) * BUFO);                    \
            }                                                                 \
        } else {                                                              \
            if (hasA) {                                                       \
                gload_lds16(pa0 + ka, lAs0 + (NA) * BUFO);                    \
                gload_lds16(pa1 + ka, lAs1 + (NA) * BUFO);                    \
                gload_lds16((const __hip_bfloat16*)Bv + b0off + ka, lBs0 + (NA) * BUFO); \
                gload_lds16((const __hip_bfloat16*)Bv + b1off + ka, lBs1 + (NA) * BUFO); \
            }                                                                 \
        }                                                                     \
        bf16x8 a[4], b[4];                                                    \
        _Pragma("unroll")                                                     \
        for (int i = 0; i < 4; ++i)                                           \
            a[i] = *(const bf16x8*)(As + (CO) * BUFO + (wm + i * 16 + lane15) * 32 + rsw); \
        _Pragma("unroll")                                                     \
        for (int j = 0; j < 4; ++j)                                           \
            b[j] = *(const bf16x8*)(Bs + (CO) * BUFO + (wn + j * 16 + lane15) * 32 + rsw); \
        _Pragma("unroll")                                                     \
        for (int i = 0; i < 4; ++i)                                           \
            _Pragma("unroll")                                                 \
            for (int j = 0; j < 4; ++j)                                       \
                acc[i][j] = MFMA16(a[i], b[j], acc[i][j]);                    \
        if constexpr (BF32) {                                                 \
            if (hasB) {                                                       \
                *(uint4*)(lBs0 + (NB) * BUFO) = cvt8_f32(g0, g1);             \
                *(uint4*)(lBs1 + (NB) * BUFO) = cvt8_f32(g2, g3);             \
            }                                                                 \
        }                                                                     \
        if (hasA) {                                                           \
            if constexpr (BF32)                                               \
                asm volatile("s_waitcnt vmcnt(2) lgkmcnt(0)" ::: "memory");   \
            else                                                              \
                asm volatile("s_waitcnt vmcnt(4) lgkmcnt(0)" ::: "memory");   \
        } else {                                                              \
            asm volatile("s_waitcnt vmcnt(0) lgkmcnt(0)" ::: "memory");       \
        }                                                                     \
        __builtin_amdgcn_s_barrier();                                         \
    }

    for (int k0 = 0; k0 < K; k0 += 96) {
        GEMM_STEP(k0,      0, 1, 2)
        GEMM_STEP(k0 + 32, 1, 2, 0)
        GEMM_STEP(k0 + 64, 2, 0, 1)
    }
#undef GEMM_STEP

    // epilogue: C/D layout col=lane&15, row=quad*4+reg
    #pragma unroll
    for (int i = 0; i < 4; ++i) {
        #pragma unroll
        for (int r = 0; r < 4; ++r) {
            const int m = m0 + wm + i * 16 + quad * 4 + r;
            if (m < M) {
                #pragma unroll
                for (int j = 0; j < 4; ++j) {
                    const int n = n0 + wn + j * 16 + lane15;
                    if constexpr (CF32)
                        ((float*)Cv)[(size_t)m * N + n] = acc[i][j][r];
                    else
                        ((__hip_bfloat16*)Cv)[(size_t)m * N + n] = __float2bfloat16(acc[i][j][r]);
                }
            }
        }
    }
}

// ---------------------------------------------------------------------------
// K2: RoPE in-place on q and k for patch tokens (s >= 1) — r6-verified.
// ---------------------------------------------------------------------------
__global__ __launch_bounds__(256) void rope_kernel(__hip_bfloat16* __restrict__ qkv)
{
    const int p = blockIdx.x;    // 0..575 patch index
    const int b = blockIdx.y;
    const int l = threadIdx.x & 63;
    const int w = threadIdx.x >> 6;

    const int jj   = l & 31;
    const float i2 = (float)((jj >> 1) * 2);
    const float dv = __expf(-i2 * 0.28782313662425576f);   // ln(10000)/32
    const float inv = 1.0f / (23.0f + 1e-8f);
    const float cx = (float)(p % 24) * inv;
    const float cy = (float)(p / 24) * inv;
    const float ang = ((l < 32) ? cx : cy) * dv;
    const float c = __cosf(ang);
    const float s = __sinf(ang);
    const int nb = (l & 32) | ((jj + 31) & 31);   // lane of (j-1)%32, same half

    const size_t rowbase = ((size_t)(b * S_LEN + 1 + p)) * F3;

    for (int pr = w; pr < 24; pr += 4) {
        const int part = pr / 12;    // 0=q, 1=k
        const int h    = pr % 12;
        const size_t off = rowbase + (size_t)part * EMB + h * DHEAD + l;
        float v  = __bfloat162float(qkv[off]);
        float vp = __shfl(v, nb, 64);
        qkv[off] = __float2bfloat16(v * c + vp * s);
    }
}

// ---------------------------------------------------------------------------
// K3: MFMA flash attention, 512 threads (8 waves), Q tile = 128 rows.
// grid (qt=5, h=12, b=32). Wave w owns q rows w*16..w*16+15 of the tile.
// Q pre-scaled by 0.125. O written with row stride ldo (aliased onto qkv's
// q-region; each block overwrites exactly the q-cells only it reads).
//
// Ps aliased onto the Qs LDS region (Qs dead after frag load): LDS 36864 B
// -> 4 blocks/CU.  P write rows are wave-private (w*16+lane15), so the P
// round-trip needs only a same-wave lgkmcnt drain.
//
// r10a T14 async-STAGE: tile t+1's K/V global loads issue before barrier B;
// barrier B is raw s_barrier + lgkmcnt(0) only (NO vmcnt drain) so the loads
// stay in flight across the compute phase.  Barrier A (__syncthreads) drains
// vmcnt right where the data is consumed (LDS staging writes).
//
// r10b swapped QK^T: sf = mfma(Kfrag, Qfrag) gives S^T[key][q]; lane owns
// q=lane15's 64 keys (16 regs + quad-folds at xor16/xor32).  Scalar m/l.
// alpha/l broadcast to O-layout rows (q=quad*4+r) via 4 lane-reads.
// ---------------------------------------------------------------------------
__global__ __launch_bounds__(512) void attn_kernel(
    const __hip_bfloat16* __restrict__ qkv,
    __hip_bfloat16* __restrict__ attn_out, int ldo)
{
    __shared__ __hip_bfloat16 Qs[128][72];     // Q frags, then aliased as Ps
    __shared__ __hip_bfloat16 Ks[64][72];
    __shared__ __hip_bfloat16 Vt[64][72];      // transposed: Vt[d][s]

    const int t      = threadIdx.x;
    const int l      = t & 63;
    const int w      = t >> 6;     // 0..7
    const int lane15 = l & 15;
    const int quad   = l >> 4;

    const int q0 = blockIdx.x * 128;
    const int h  = blockIdx.y;
    const int b  = blockIdx.z;

    // staging index split (fixed per thread)
    const int krow = t >> 3, kseg = t & 7;   // K: row 0..63, 16B chunk 0..7
    const int vs   = t & 63, vdg = t >> 6;   // V: s 0..63, dim-group 0..7

    // ---- issue tile-0 K/V prefetch ----
    uint4 ku, vu;
    {
        int gk = krow; if (gk > S_LEN - 1) gk = S_LEN - 1;
        ku = ((const uint4*)(qkv + (size_t)(b * S_LEN + gk) * F3 + EMB + h * DHEAD))[kseg];
        int gv = vs;  if (gv > S_LEN - 1) gv = S_LEN - 1;
        vu = ((const uint4*)(qkv + (size_t)(b * S_LEN + gv) * F3 + 2 * EMB + h * DHEAD))[vdg];
    }

    // ---- stage Q (scaled): row = t>>2 (0..127), seg = t&3 (16 elems) ----
    {
        const int row = t >> 2, seg = t & 3;
        int gq = q0 + row; if (gq > S_LEN - 1) gq = S_LEN - 1;
        const uint4* src = (const uint4*)(qkv + (size_t)(b * S_LEN + gq) * F3 + h * DHEAD + seg * 16);
        uint4 u0 = src[0], u1 = src[1];
        const __hip_bfloat16* e0 = (const __hip_bfloat16*)&u0;
        const __hip_bfloat16* e1 = (const __hip_bfloat16*)&u1;
        #pragma unroll
        for (int i = 0; i < 8; ++i) {
            Qs[row][seg * 16 + i]     = __float2bfloat16(__bfloat162float(e0[i]) * 0.125f);
            Qs[row][seg * 16 + 8 + i] = __float2bfloat16(__bfloat162float(e1[i]) * 0.125f);
        }
    }
    __syncthreads();

    // B-operand frags for Q: B[n=lane&15 (q row)][k=quad*8+j]  (held whole loop)
    bf16x8 qf0 = *(const bf16x8*)&Qs[w * 16 + lane15][quad * 8];
    bf16x8 qf1 = *(const bf16x8*)&Qs[w * 16 + lane15][32 + quad * 8];

    f32x4 o[4] = {};                       // O[q=quad*4+r][d=ci*16+lane15]
    float m_i = -3.0e38f;                  // softmax state for q = lane15 (scalar)
    float l_i = 0.f;

    for (int ti = 0; ti < NT_KV; ++ti) {
        __syncthreads();   // A: prior tile's LDS reads done; vmcnt drain = consume prefetch
        // ---- write prefetched K tile: Ks[krow][kseg*8..] ----
        *(uint4*)&Ks[krow][kseg * 8] = ku;
        // ---- write prefetched V tile transposed ----
        {
            const __hip_bfloat16* e0 = (const __hip_bfloat16*)&vu;
            #pragma unroll
            for (int i = 0; i < 8; ++i)
                Vt[vdg * 8 + i][vs] = e0[i];
        }
        // ---- issue NEXT tile's K/V prefetch (stays in flight across B) ----
        if (ti + 1 < NT_KV) {
            int gk = (ti + 1) * 64 + krow; if (gk > S_LEN - 1) gk = S_LEN - 1;
            ku = ((const uint4*)(qkv + (size_t)(b * S_LEN + gk) * F3 + EMB + h * DHEAD))[kseg];
            int gv = (ti + 1) * 64 + vs;  if (gv > S_LEN - 1) gv = S_LEN - 1;
            vu = ((const uint4*)(qkv + (size_t)(b * S_LEN + gv) * F3 + 2 * EMB + h * DHEAD))[vdg];
        }
        // B: LDS writes visible; do NOT drain vmcnt (prefetch in flight)
        asm volatile("s_waitcnt lgkmcnt(0)" ::: "memory");
        __builtin_amdgcn_s_barrier();
        asm volatile("" ::: "memory");

        // ---- S^T = K Q^T: sf[nt][r] = S[key=nt*16+quad*4+r][q=lane15] ----
        f32x4 sf[4];
        #pragma unroll
        for (int nt = 0; nt < 4; ++nt) {
            f32x4 z = {0.f, 0.f, 0.f, 0.f};
            bf16x8 k0f = *(const bf16x8*)&Ks[nt * 16 + lane15][quad * 8];
            bf16x8 k1f = *(const bf16x8*)&Ks[nt * 16 + lane15][32 + quad * 8];
            z = MFMA16(k0f, qf0, z);
            z = MFMA16(k1f, qf1, z);
            sf[nt] = z;
        }
        const int s0 = ti * 64;
        #pragma unroll
        for (int nt = 0; nt < 4; ++nt)
            #pragma unroll
            for (int r = 0; r < 4; ++r)
                if (s0 + nt * 16 + quad * 4 + r >= S_LEN) sf[nt][r] = -1e30f;

        // ---- row max for q=lane15: 16 local + fold across quads ----
        float mx = fmaxf(fmaxf(sf[0][0], sf[0][1]), fmaxf(sf[0][2], sf[0][3]));
        #pragma unroll
        for (int nt = 1; nt < 4; ++nt)
            mx = fmaxf(mx, fmaxf(fmaxf(sf[nt][0], sf[nt][1]), fmaxf(sf[nt][2], sf[nt][3])));
        mx = fmaxf(mx, __shfl_xor(mx, 16, 64));
        mx = fmaxf(mx, __shfl_xor(mx, 32, 64));

        const float mnew  = fmaxf(m_i, mx);
        const float alpha = __expf(m_i - mnew);
        m_i = mnew;

        // ---- P = exp(S - m), row sum ----
        float sum = 0.f;
        #pragma unroll
        for (int nt = 0; nt < 4; ++nt) {
            #pragma unroll
            for (int r = 0; r < 4; ++r) {
                sf[nt][r] = __expf(sf[nt][r] - mnew);
                sum += sf[nt][r];
            }
        }
        sum += __shfl_xor(sum, 16, 64);
        sum += __shfl_xor(sum, 32, 64);
        l_i = l_i * alpha + sum;

        // ---- broadcast alpha to O-layout rows (q = quad*4+r lives in lane quad*4+r) ----
        float af[4];
        #pragma unroll
        for (int r = 0; r < 4; ++r)
            af[r] = __shfl(alpha, quad * 4 + r, 64);
        #pragma unroll
        for (int ci = 0; ci < 4; ++ci)
            #pragma unroll
            for (int r = 0; r < 4; ++r)
                o[ci][r] *= af[r];

        // ---- P: S^T lane layout -> LDS [q][key] (wave-private rows) ----
        #pragma unroll
        for (int nt = 0; nt < 4; ++nt)
            #pragma unroll
            for (int r = 0; r < 4; ++r)
                Qs[w * 16 + lane15][nt * 16 + quad * 4 + r] = __float2bfloat16(sf[nt][r]);
        asm volatile("s_waitcnt lgkmcnt(0)" ::: "memory");

        // ---- O += P V ----
        #pragma unroll
        for (int s32 = 0; s32 < 2; ++s32) {
            bf16x8 pa = *(const bf16x8*)&Qs[w * 16 + lane15][s32 * 32 + quad * 8];
            #pragma unroll
            for (int ci = 0; ci < 4; ++ci) {
                bf16x8 vb = *(const bf16x8*)&Vt[ci * 16 + lane15][s32 * 32 + quad * 8];
                o[ci] = MFMA16(pa, vb, o[ci]);
            }
        }
    }

    // ---- epilogue: O / l -> attn_out; l for row q=quad*4+r from lane quad*4+r ----
    #pragma unroll
    for (int r = 0; r < 4; ++r) {
        const float lr = __shfl(l_i, quad * 4 + r, 64);
        const int q = q0 + w * 16 + quad * 4 + r;
        if (q < S_LEN) {
            const float rl = 1.0f / lr;
            #pragma unroll
            for (int ci = 0; ci < 4; ++ci) {
                attn_out[(size_t)(b * S_LEN + q) * ldo + h * DHEAD + ci * 16 + lane15] =
                    __float2bfloat16(o[ci][r] * rl);
            }
        }
    }
}

// ---------------------------------------------------------------------------
extern "C" void kernel_launch(void* const* d_in, const int* in_sizes, int n_in,
                              void* d_out, int out_size, void* d_ws, size_t ws_size,
                              hipStream_t stream) {
    const float* x      = (const float*)d_in[0];
    const float* w_qkv  = (const float*)d_in[1];
    const float* w_proj = (const float*)d_in[2];
    for (int i = 0; i < n_in; ++i) {
        if      (in_sizes[i] == 32 * S_LEN * EMB) x      = (const float*)d_in[i];
        else if (in_sizes[i] == F3 * EMB)         w_qkv  = (const float*)d_in[i];
        else if (in_sizes[i] == EMB * EMB)        w_proj = (const float*)d_in[i];
    }
    float* out = (float*)d_out;     // fp32 output (r6-verified)

    const int Mrows = 32 * S_LEN;           // 18464
    const int NX    = Mrows * EMB;          // 14,180,352 (mult of 8)
    const int NWQ   = F3 * EMB;             // 1,769,472  (mult of 8)

    __hip_bfloat16* qkv = (__hip_bfloat16*)d_ws;        // [M][2304] bf16, 81.1 MiB
    // d_out as scratch until K4 overwrites it: xb (28.4 MB) + wb (3.4 MB) < 56.7 MB
    __hip_bfloat16* xb  = (__hip_bfloat16*)d_out;
    __hip_bfloat16* wb  = xb + (size_t)NX;

    // C1/C2: fp32 -> bf16 converts into d_out scratch
    cvt_f32_bf16<<<NX / 8 / 256, 256, 0, stream>>>(x, xb, NX / 8);
    cvt_f32_bf16<<<NWQ / 8 / 256, 256, 0, stream>>>(w_qkv, wb, NWQ / 8);
    // K1: qkv = xb @ wb^T  (pure-bf16 DMA staging, bf16 C)
    gemm_a_dma<false, false><<<dim3(F3 / 128, (Mrows + 127) / 128), 256, 0, stream>>>(
        xb, EMB, wb, EMB, qkv, Mrows, F3, EMB);
    // K2: RoPE on q,k patch rows
    rope_kernel<<<dim3(576, 32), 256, 0, stream>>>(qkv);
    // K3: attention (512 thr, 128-row Q tiles); O overwrites q-region of qkv
    attn_kernel<<<dim3((S_LEN + 127) / 128, NHEAD, 32), 512, 0, stream>>>(qkv, qkv, F3);
    // K4: out = O @ bf16(w_proj)^T  (A DMA bf16 stride F3; B fp32 convert; C fp32)
    gemm_a_dma<true, true><<<dim3(EMB / 128, (Mrows + 127) / 128), 256, 0, stream>>>(
        qkv, F3, w_proj, EMB, out, Mrows, EMB, EMB);
}